// Round 7
// baseline (662.937 us; speedup 1.0000x reference)
//
#include <hip/hip_runtime.h>
#include <hip/hip_bf16.h>

// ---------------------------------------------------------------------------
// EDACrossIMUEncoder fused forward (MI355X / gfx950) — v4
//
// Seq-len == 1 => softmax(1x1)==1 => MHA(q,k) == k @ (Wo Wv)^T + (Wo bv + bo).
// v1 522us (I$-thrash, 4 blk/CU) -> v3 336us (rolled, 8 blk/CU) both passed.
// v3 counters: MfmaUtil 7.7%, VALUBusy 9.7%, HBM 6.4% -> ~83% stall: rolled
//   loops serialize (global B-frag load -> waitcnt -> MFMA) per iteration,
//   no cross-iteration overlap; 2 waves/SIMD can't hide it.
// v4: 2-deep ping-pong register prefetch in proj/attn/head loops; FFN hoists
//   W2 loads above FFN1 MFMAs + batches St/W1 loads; prep_combine
//   parallelized (4 waves x ILP2 + LDS reduce; was a 128-FMA serial chain).
// 32x32x16 bf16 MFMA layouts (learn_hip m74/m101 verified):
//   A: row=lane&31, k=(lane>>5)*8+j ; B: col=lane&31, k=(lane>>5)*8+j
//   C/D: col=lane&31, row=(r&3)+8*(r>>2)+4*(lane>>5)
// Requires ws_size >= 1.25 MB.
// ---------------------------------------------------------------------------

typedef __bf16 bf16x8_t __attribute__((ext_vector_type(8)));
typedef float  f32x16_t __attribute__((ext_vector_type(16)));
typedef float  f32x4_t  __attribute__((ext_vector_type(4)));

#define DEV static __device__ __forceinline__

DEV f32x16_t mfma_op(bf16x8_t a, bf16x8_t b, f32x16_t c) {
  return __builtin_amdgcn_mfma_f32_32x32x16_bf16(a, b, c, 0, 0, 0);
}

DEV bf16x8_t cvt2(f32x4_t t0, f32x4_t t1) {
  bf16x8_t a;
  a[0] = (__bf16)t0[0]; a[1] = (__bf16)t0[1]; a[2] = (__bf16)t0[2]; a[3] = (__bf16)t0[3];
  a[4] = (__bf16)t1[0]; a[5] = (__bf16)t1[1]; a[6] = (__bf16)t1[2]; a[7] = (__bf16)t1[3];
  return a;
}

// ---- packed-weight element offsets (bf16 elems; one chunk = 64 lanes x 8 = 512) ----
constexpr int PO_PROJ_E = 0;                     // K=512 N=128 : 128 chunks
constexpr int PO_PROJ_I = PO_PROJ_E + 128 * 512;
constexpr int PO_ATTN   = PO_PROJ_I + 128 * 512; // 4 x (K=128 N=128 : 32 chunks)
constexpr int PO_FFN1   = PO_ATTN   + 4 * 32 * 512; // 4 x (K=128 N=256 : 64 chunks)
constexpr int PO_FFN2   = PO_FFN1   + 4 * 64 * 512; // 4 x (K=256 N=128 : 64 chunks)
constexpr int PO_HEAD   = PO_FFN2   + 4 * 64 * 512; // K=256 N=128 : 64 chunks
constexpr int WS_BC_F      = 4 * 128 * 128;
constexpr int WS_PACK_BYTE = (WS_BC_F + 4 * 128) * 4; // = 264192 (16B aligned)

#define PITCH_S 136   // bf16/row state scratch (128+8); 272B = 17*16
#define PITCH_H 40    // bf16/row FFN-h scratch (32+8);   80B = 5*16

// ---------------------------------------------------------------------------
// prep 1: Wc = Wo @ Wv (f32), bc = Wo @ bv + bo.  512 blocks x 256 thr.
// wave w sums p in [w*32,w*32+32) with 2-way ILP; LDS tree-reduce.
// ---------------------------------------------------------------------------
__global__ __launch_bounds__(256) void prep_combine(
    const float* __restrict__ e2i_wqkv, const float* __restrict__ e2i_wo,
    const float* __restrict__ e2i_bqkv, const float* __restrict__ e2i_bo,
    const float* __restrict__ i2e_wqkv, const float* __restrict__ i2e_wo,
    const float* __restrict__ i2e_bqkv, const float* __restrict__ i2e_bo,
    float* __restrict__ wsf) {
  const int blk = blockIdx.x;
  const int d = blk >> 7, n = blk & 127, l = d & 1;
  const float* wqkv = (d < 2) ? e2i_wqkv : i2e_wqkv;
  const float* wo   = (d < 2) ? e2i_wo   : i2e_wo;
  const float* bqkv = (d < 2) ? e2i_bqkv : i2e_bqkv;
  const float* bo   = (d < 2) ? e2i_bo   : i2e_bo;
  const float* wv    = wqkv + l * 3 * 128 * 128 + 2 * 128 * 128;
  const float* worow = wo + l * 128 * 128 + n * 128;
  const float* bv    = bqkv + l * 3 * 128 + 2 * 128;
  const int tid = threadIdx.x, lane = tid & 63, w = tid >> 6;
  float a0 = 0.f, a1 = 0.f, c0 = 0.f, c1 = 0.f;
#pragma unroll 4
  for (int p = w * 32; p < w * 32 + 32; p += 2) {
    float wa = worow[p], wb = worow[p + 1];
    a0 += wa * wv[p * 128 + lane];
    a1 += wa * wv[p * 128 + 64 + lane];
    c0 += wb * wv[(p + 1) * 128 + lane];
    c1 += wb * wv[(p + 1) * 128 + 64 + lane];
  }
  a0 += c0; a1 += c1;
  __shared__ float red[4][2][64];
  red[w][0][lane] = a0; red[w][1][lane] = a1;
  __syncthreads();
  if (w == 0) {
    a0 = red[0][0][lane] + red[1][0][lane] + red[2][0][lane] + red[3][0][lane];
    a1 = red[0][1][lane] + red[1][1][lane] + red[2][1][lane] + red[3][1][lane];
    wsf[d * 16384 + n * 128 + lane]      = a0;
    wsf[d * 16384 + n * 128 + 64 + lane] = a1;
    float bacc = worow[lane] * bv[lane] + worow[64 + lane] * bv[64 + lane];
    for (int off = 1; off < 64; off <<= 1) bacc += __shfl_xor(bacc, off, 64);
    if (lane == 0) wsf[WS_BC_F + d * 128 + n] = bacc + bo[l * 128 + n];
  }
}

// ---------------------------------------------------------------------------
// prep 2: pack weights into bf16 B-fragment order (unchanged, proven).
// ---------------------------------------------------------------------------
__global__ __launch_bounds__(64) void prep_pack(
    const float* __restrict__ proj_e, const float* __restrict__ proj_i,
    const float* __restrict__ ffn_e_w1, const float* __restrict__ ffn_i_w1,
    const float* __restrict__ ffn_e_w2, const float* __restrict__ ffn_i_w2,
    const float* __restrict__ out_w, const float* __restrict__ wsf,
    __bf16* __restrict__ pack) {
  const int b = blockIdx.x, lane = threadIdx.x;
  const float* src; int K, sh, dstOff, c;
  if (b < 128)      { src = proj_e; K = 512; sh = 2; dstOff = PO_PROJ_E; c = b; }
  else if (b < 256) { src = proj_i; K = 512; sh = 2; dstOff = PO_PROJ_I; c = b - 128; }
  else if (b < 384) { int i = (b - 256) >> 5; c = (b - 256) & 31;
                      src = wsf + i * 16384; K = 128; sh = 2;
                      dstOff = PO_ATTN + i * 32 * 512; }
  else if (b < 640) { int i = (b - 384) >> 6; c = (b - 384) & 63;
                      src = ((i < 2) ? ffn_e_w1 : ffn_i_w1) + (i & 1) * 256 * 128;
                      K = 128; sh = 3; dstOff = PO_FFN1 + i * 64 * 512; }
  else if (b < 896) { int i = (b - 640) >> 6; c = (b - 640) & 63;
                      src = ((i < 2) ? ffn_e_w2 : ffn_i_w2) + (i & 1) * 128 * 256;
                      K = 256; sh = 2; dstOff = PO_FFN2 + i * 64 * 512; }
  else              { c = b - 896; src = out_w; K = 256; sh = 2; dstOff = PO_HEAD; }
  const int kt = c >> sh, nt = c & ((1 << sh) - 1);
  const int n  = nt * 32 + (lane & 31);
  const int kb = kt * 16 + (lane >> 5) * 8;
  const float* s = src + n * K + kb;
  bf16x8_t v;
#pragma unroll
  for (int j = 0; j < 8; ++j) v[j] = (__bf16)s[j];
  *(bf16x8_t*)&pack[dstOff + (c * 64 + lane) * 8] = v;
}

// ---------------------------------------------------------------------------
// main fused kernel v4: 2048 blocks x 64 threads (1 wave = 32 batch rows).
// LDS 19968B -> 8 blocks/CU. Ping-pong prefetched GEMM loops.
// ---------------------------------------------------------------------------
__global__ __launch_bounds__(64, 2) void fused_fwd(
    const float* __restrict__ tokens,
    const float* __restrict__ eda_proj_b, const float* __restrict__ eda_cls,
    const float* __restrict__ imu_proj_b, const float* __restrict__ imu_cls,
    const float* __restrict__ ffn_eda_b1, const float* __restrict__ ffn_eda_b2,
    const float* __restrict__ ffn_imu_b1, const float* __restrict__ ffn_imu_b2,
    const float* __restrict__ ln_e1g, const float* __restrict__ ln_e1b,
    const float* __restrict__ ln_e2g, const float* __restrict__ ln_e2b,
    const float* __restrict__ ln_i1g, const float* __restrict__ ln_i1b,
    const float* __restrict__ ln_i2g, const float* __restrict__ ln_i2b,
    const float* __restrict__ out_b, const float* __restrict__ out_ln_g,
    const float* __restrict__ out_ln_b,
    const float* __restrict__ bc_all,
    const __bf16* __restrict__ pack,
    float* __restrict__ out) {
  alignas(16) __shared__ __bf16 smem[2 * 32 * PITCH_S + 32 * PITCH_H];
  __bf16* Se = smem;
  __bf16* Si = smem + 32 * PITCH_S;
  __bf16* Sh = smem + 2 * 32 * PITCH_S;

  const int lane = threadIdx.x;
  const int l31 = lane & 31, lh = lane >> 5;
  const int rowbase = blockIdx.x * 32;

  auto crowf = [&](int r) { return (r & 3) + ((r >> 2) << 3) + (lh << 2); };

  auto layer_norm = [&](f32x16_t (&A)[4], const float* g, const float* bb) {
    float gv[4], bv[4];
#pragma unroll
    for (int nt = 0; nt < 4; ++nt) { gv[nt] = g[nt * 32 + l31]; bv[nt] = bb[nt * 32 + l31]; }
#pragma unroll
    for (int r = 0; r < 16; ++r) {
      float s = 0.f, s2 = 0.f;
#pragma unroll
      for (int nt = 0; nt < 4; ++nt) { float v = A[nt][r]; s += v; s2 += v * v; }
#pragma unroll
      for (int off = 1; off < 32; off <<= 1) {
        s  += __shfl_xor(s, off, 64);
        s2 += __shfl_xor(s2, off, 64);
      }
      const float mean = s * (1.f / 128.f);
      const float var  = s2 * (1.f / 128.f) - mean * mean;
      const float rs   = rsqrtf(var + 1e-5f);
#pragma unroll
      for (int nt = 0; nt < 4; ++nt)
        A[nt][r] = (A[nt][r] - mean) * rs * gv[nt] + bv[nt];
    }
  };

  auto store_state = [&](f32x16_t (&A)[4], __bf16* S) {
#pragma unroll
    for (int nt = 0; nt < 4; ++nt)
#pragma unroll
      for (int r = 0; r < 16; ++r)
        S[crowf(r) * PITCH_S + nt * 32 + l31] = (__bf16)A[nt][r];
  };

  // ---------------- projections: state = tok @ Wproj^T + b + cls ----------------
#pragma unroll 1
  for (int sel = 0; sel < 2; ++sel) {
    const float* pb = sel ? imu_proj_b : eda_proj_b;
    const float* pc = sel ? imu_cls : eda_cls;
    __bf16* Sd = sel ? Si : Se;
    const __bf16* pw = pack + (sel ? PO_PROJ_I : PO_PROJ_E);
    f32x16_t acc[4];
#pragma unroll
    for (int nt = 0; nt < 4; ++nt) {
      const float bias = pb[nt * 32 + l31] + pc[nt * 32 + l31];
#pragma unroll
      for (int r = 0; r < 16; ++r) acc[nt][r] = bias;
    }
    const float* t0 = tokens + (size_t)(rowbase + l31) * 1024 + sel * 512 + lh * 8;
    // ping-pong pipeline: set A preload (kt=0)
    f32x4_t tA0 = *(const f32x4_t*)t0, tA1 = *(const f32x4_t*)(t0 + 4);
    const __bf16* pA = pw + lane * 8;
    bf16x8_t wA0 = *(const bf16x8_t*)(pA);
    bf16x8_t wA1 = *(const bf16x8_t*)(pA + 512);
    bf16x8_t wA2 = *(const bf16x8_t*)(pA + 1024);
    bf16x8_t wA3 = *(const bf16x8_t*)(pA + 1536);
#pragma unroll 1
    for (int kt = 0; kt < 32; kt += 2) {
      // issue set B (kt+1)
      const float* tb = t0 + (kt + 1) * 16;
      f32x4_t tB0 = *(const f32x4_t*)tb, tB1 = *(const f32x4_t*)(tb + 4);
      const __bf16* pB = pw + ((kt + 1) * 4 * 64 + lane) * 8;
      bf16x8_t wB0 = *(const bf16x8_t*)(pB);
      bf16x8_t wB1 = *(const bf16x8_t*)(pB + 512);
      bf16x8_t wB2 = *(const bf16x8_t*)(pB + 1024);
      bf16x8_t wB3 = *(const bf16x8_t*)(pB + 1536);
      // compute set A
      {
        bf16x8_t a = cvt2(tA0, tA1);
        acc[0] = mfma_op(a, wA0, acc[0]);
        acc[1] = mfma_op(a, wA1, acc[1]);
        acc[2] = mfma_op(a, wA2, acc[2]);
        acc[3] = mfma_op(a, wA3, acc[3]);
      }
      // issue set A (kt+2, clamped dup on last iter — values unused)
      const int ka = (kt + 2 < 32) ? kt + 2 : kt;
      const float* ta = t0 + ka * 16;
      tA0 = *(const f32x4_t*)ta; tA1 = *(const f32x4_t*)(ta + 4);
      pA = pw + (ka * 4 * 64 + lane) * 8;
      wA0 = *(const bf16x8_t*)(pA);
      wA1 = *(const bf16x8_t*)(pA + 512);
      wA2 = *(const bf16x8_t*)(pA + 1024);
      wA3 = *(const bf16x8_t*)(pA + 1536);
      // compute set B
      {
        bf16x8_t a = cvt2(tB0, tB1);
        acc[0] = mfma_op(a, wB0, acc[0]);
        acc[1] = mfma_op(a, wB1, acc[1]);
        acc[2] = mfma_op(a, wB2, acc[2]);
        acc[3] = mfma_op(a, wB3, acc[3]);
      }
    }
    store_state(acc, Sd);
  }

  // ---------------- transformer layers ----------------
#pragma unroll 1
  for (int l = 0; l < 2; ++l) {
#pragma unroll 1
    for (int mod = 0; mod < 2; ++mod) {
      const __bf16* Sx = mod ? Se : Si;
      __bf16* St = mod ? Si : Se;
      const int widx = mod * 2 + l;
      const __bf16* attn_w = pack + PO_ATTN + widx * 32 * 512;
      const __bf16* ffn1_w = pack + PO_FFN1 + widx * 64 * 512;
      const __bf16* ffn2_w = pack + PO_FFN2 + widx * 64 * 512;
      const float* bc  = bc_all + widx * 128;
      const float* b1  = (mod ? ffn_imu_b1 : ffn_eda_b1) + l * 256;
      const float* b2  = (mod ? ffn_imu_b2 : ffn_eda_b2) + l * 128;
      const float* g1  = (mod ? ln_i1g : ln_e1g) + l * 128;
      const float* bb1 = (mod ? ln_i1b : ln_e1b) + l * 128;
      const float* g2  = (mod ? ln_i2g : ln_e2g) + l * 128;
      const float* bb2 = (mod ? ln_i2b : ln_e2b) + l * 128;

      // -- attention-linear: acc = bc + residual; += x_other @ Wc^T; LN1 --
      f32x16_t acc[4];
#pragma unroll
      for (int nt = 0; nt < 4; ++nt) {
        const float bv = bc[nt * 32 + l31];
#pragma unroll
        for (int r = 0; r < 16; ++r)
          acc[nt][r] = bv + (float)St[crowf(r) * PITCH_S + nt * 32 + l31];
      }
      {
        bf16x8_t aA = *(const bf16x8_t*)&Sx[l31 * PITCH_S + lh * 8];
        const __bf16* pA = attn_w + lane * 8;
        bf16x8_t wA0 = *(const bf16x8_t*)(pA);
        bf16x8_t wA1 = *(const bf16x8_t*)(pA + 512);
        bf16x8_t wA2 = *(const bf16x8_t*)(pA + 1024);
        bf16x8_t wA3 = *(const bf16x8_t*)(pA + 1536);
#pragma unroll 1
        for (int kt = 0; kt < 8; kt += 2) {
          bf16x8_t aB = *(const bf16x8_t*)&Sx[l31 * PITCH_S + (kt + 1) * 16 + lh * 8];
          const __bf16* pB = attn_w + ((kt + 1) * 4 * 64 + lane) * 8;
          bf16x8_t wB0 = *(const bf16x8_t*)(pB);
          bf16x8_t wB1 = *(const bf16x8_t*)(pB + 512);
          bf16x8_t wB2 = *(const bf16x8_t*)(pB + 1024);
          bf16x8_t wB3 = *(const bf16x8_t*)(pB + 1536);
          acc[0] = mfma_op(aA, wA0, acc[0]);
          acc[1] = mfma_op(aA, wA1, acc[1]);
          acc[2] = mfma_op(aA, wA2, acc[2]);
          acc[3] = mfma_op(aA, wA3, acc[3]);
          const int ka = (kt + 2 < 8) ? kt + 2 : kt;
          aA = *(const bf16x8_t*)&Sx[l31 * PITCH_S + ka * 16 + lh * 8];
          pA = attn_w + (ka * 4 * 64 + lane) * 8;
          wA0 = *(const bf16x8_t*)(pA);
          wA1 = *(const bf16x8_t*)(pA + 512);
          wA2 = *(const bf16x8_t*)(pA + 1024);
          wA3 = *(const bf16x8_t*)(pA + 1536);
          acc[0] = mfma_op(aB, wB0, acc[0]);
          acc[1] = mfma_op(aB, wB1, acc[1]);
          acc[2] = mfma_op(aB, wB2, acc[2]);
          acc[3] = mfma_op(aB, wB3, acc[3]);
        }
      }
      layer_norm(acc, g1, bb1);
      store_state(acc, St);  // e1 in LDS (A-source) AND in acc (f32 residual)

      // -- FFN: yacc = b2 + e1; per 32-col chunk: batched W1/St loads + W2 hoist --
      f32x16_t yacc[4];
#pragma unroll
      for (int nt = 0; nt < 4; ++nt) {
        const float bv = b2[nt * 32 + l31];
#pragma unroll
        for (int r = 0; r < 16; ++r) yacc[nt][r] = bv + acc[nt][r];
      }
#pragma unroll 1
      for (int hc = 0; hc < 8; ++hc) {
        // batch-issue: 8 St A-frags (LDS), 8 W1 chunks, 8 W2 chunks (all independent)
        bf16x8_t s0 = *(const bf16x8_t*)&St[l31 * PITCH_S + 0 * 16 + lh * 8];
        bf16x8_t s1 = *(const bf16x8_t*)&St[l31 * PITCH_S + 1 * 16 + lh * 8];
        bf16x8_t s2 = *(const bf16x8_t*)&St[l31 * PITCH_S + 2 * 16 + lh * 8];
        bf16x8_t s3 = *(const bf16x8_t*)&St[l31 * PITCH_S + 3 * 16 + lh * 8];
        bf16x8_t s4 = *(const bf16x8_t*)&St[l31 * PITCH_S + 4 * 16 + lh * 8];
        bf16x8_t s5 = *(const bf16x8_t*)&St[l31 * PITCH_S + 5 * 16 + lh * 8];
        bf16x8_t s6 = *(const bf16x8_t*)&St[l31 * PITCH_S + 6 * 16 + lh * 8];
        bf16x8_t s7 = *(const bf16x8_t*)&St[l31 * PITCH_S + 7 * 16 + lh * 8];
        const __bf16* w1b = ffn1_w + (hc * 64 + lane) * 8;      // chunk kt*8+hc
        bf16x8_t u0 = *(const bf16x8_t*)(w1b + 0 * 8 * 512);
        bf16x8_t u1 = *(const bf16x8_t*)(w1b + 1 * 8 * 512);
        bf16x8_t u2 = *(const bf16x8_t*)(w1b + 2 * 8 * 512);
        bf16x8_t u3 = *(const bf16x8_t*)(w1b + 3 * 8 * 512);
        bf16x8_t u4 = *(const bf16x8_t*)(w1b + 4 * 8 * 512);
        bf16x8_t u5 = *(const bf16x8_t*)(w1b + 5 * 8 * 512);
        bf16x8_t u6 = *(const bf16x8_t*)(w1b + 6 * 8 * 512);
        bf16x8_t u7 = *(const bf16x8_t*)(w1b + 7 * 8 * 512);
        const __bf16* w2b = ffn2_w + (hc * 8 * 64 + lane) * 8;  // chunks hc*8 + j
        bf16x8_t v0 = *(const bf16x8_t*)(w2b + 0 * 512);
        bf16x8_t v1 = *(const bf16x8_t*)(w2b + 1 * 512);
        bf16x8_t v2 = *(const bf16x8_t*)(w2b + 2 * 512);
        bf16x8_t v3 = *(const bf16x8_t*)(w2b + 3 * 512);
        bf16x8_t v4 = *(const bf16x8_t*)(w2b + 4 * 512);
        bf16x8_t v5 = *(const bf16x8_t*)(w2b + 5 * 512);
        bf16x8_t v6 = *(const bf16x8_t*)(w2b + 6 * 512);
        bf16x8_t v7 = *(const bf16x8_t*)(w2b + 7 * 512);
        // FFN1: h = relu(e1 @ W1^T + b1[hc])
        f32x16_t h;
        {
          const float hb = b1[hc * 32 + l31];
#pragma unroll
          for (int r = 0; r < 16; ++r) h[r] = hb;
        }
        h = mfma_op(s0, u0, h); h = mfma_op(s1, u1, h);
        h = mfma_op(s2, u2, h); h = mfma_op(s3, u3, h);
        h = mfma_op(s4, u4, h); h = mfma_op(s5, u5, h);
        h = mfma_op(s6, u6, h); h = mfma_op(s7, u7, h);
#pragma unroll
        for (int r = 0; r < 16; ++r)
          Sh[crowf(r) * PITCH_H + l31] = (__bf16)fmaxf(h[r], 0.f);
        // FFN2 partial: yacc += h @ W2^T  (W2 already in regs)
        bf16x8_t ah0 = *(const bf16x8_t*)&Sh[l31 * PITCH_H + lh * 8];
        bf16x8_t ah1 = *(const bf16x8_t*)&Sh[l31 * PITCH_H + 16 + lh * 8];
        yacc[0] = mfma_op(ah0, v0, yacc[0]);
        yacc[1] = mfma_op(ah0, v1, yacc[1]);
        yacc[2] = mfma_op(ah0, v2, yacc[2]);
        yacc[3] = mfma_op(ah0, v3, yacc[3]);
        yacc[0] = mfma_op(ah1, v4, yacc[0]);
        yacc[1] = mfma_op(ah1, v5, yacc[1]);
        yacc[2] = mfma_op(ah1, v6, yacc[2]);
        yacc[3] = mfma_op(ah1, v7, yacc[3]);
      }
      layer_norm(yacc, g2, bb2);
      store_state(yacc, St);
    }
  }

  // ---------------- head: out = relu(LN(concat(eda,imu) @ out_w^T + out_b)) ----------------
  {
    f32x16_t acc[4];
#pragma unroll
    for (int nt = 0; nt < 4; ++nt) {
      const float bv = out_b[nt * 32 + l31];
#pragma unroll
      for (int r = 0; r < 16; ++r) acc[nt][r] = bv;
    }
    const __bf16* hw = pack + PO_HEAD;
    bf16x8_t aA = *(const bf16x8_t*)&Se[l31 * PITCH_S + lh * 8];
    const __bf16* pA = hw + lane * 8;
    bf16x8_t wA0 = *(const bf16x8_t*)(pA);
    bf16x8_t wA1 = *(const bf16x8_t*)(pA + 512);
    bf16x8_t wA2 = *(const bf16x8_t*)(pA + 1024);
    bf16x8_t wA3 = *(const bf16x8_t*)(pA + 1536);
#pragma unroll 1
    for (int kt = 0; kt < 16; kt += 2) {
      const __bf16* SaB = (kt + 1 < 8) ? Se : Si;
      bf16x8_t aB = *(const bf16x8_t*)&SaB[l31 * PITCH_S + ((kt + 1) & 7) * 16 + lh * 8];
      const __bf16* pB = hw + ((kt + 1) * 4 * 64 + lane) * 8;
      bf16x8_t wB0 = *(const bf16x8_t*)(pB);
      bf16x8_t wB1 = *(const bf16x8_t*)(pB + 512);
      bf16x8_t wB2 = *(const bf16x8_t*)(pB + 1024);
      bf16x8_t wB3 = *(const bf16x8_t*)(pB + 1536);
      acc[0] = mfma_op(aA, wA0, acc[0]);
      acc[1] = mfma_op(aA, wA1, acc[1]);
      acc[2] = mfma_op(aA, wA2, acc[2]);
      acc[3] = mfma_op(aA, wA3, acc[3]);
      const int ka = (kt + 2 < 16) ? kt + 2 : kt;
      const __bf16* SaA = (ka < 8) ? Se : Si;
      aA = *(const bf16x8_t*)&SaA[l31 * PITCH_S + (ka & 7) * 16 + lh * 8];
      pA = hw + (ka * 4 * 64 + lane) * 8;
      wA0 = *(const bf16x8_t*)(pA);
      wA1 = *(const bf16x8_t*)(pA + 512);
      wA2 = *(const bf16x8_t*)(pA + 1024);
      wA3 = *(const bf16x8_t*)(pA + 1536);
      acc[0] = mfma_op(aB, wB0, acc[0]);
      acc[1] = mfma_op(aB, wB1, acc[1]);
      acc[2] = mfma_op(aB, wB2, acc[2]);
      acc[3] = mfma_op(aB, wB3, acc[3]);
    }
    layer_norm(acc, out_ln_g, out_ln_b);
#pragma unroll
    for (int nt = 0; nt < 4; ++nt)
#pragma unroll
      for (int r = 0; r < 16; ++r)
        out[(rowbase + crowf(r)) * 128 + nt * 32 + l31] = fmaxf(acc[nt][r], 0.f);
  }
}

// ---------------------------------------------------------------------------
extern "C" void kernel_launch(void* const* d_in, const int* in_sizes, int n_in,
                              void* d_out, int out_size, void* d_ws, size_t ws_size,
                              hipStream_t stream) {
  const float* tokens     = (const float*)d_in[0];
  const float* eda_proj_w = (const float*)d_in[1];
  const float* eda_proj_b = (const float*)d_in[2];
  const float* imu_proj_w = (const float*)d_in[3];
  const float* imu_proj_b = (const float*)d_in[4];
  const float* eda_cls    = (const float*)d_in[5];
  const float* imu_cls    = (const float*)d_in[6];
  const float* e2i_wqkv   = (const float*)d_in[7];
  const float* e2i_bqkv   = (const float*)d_in[8];
  const float* e2i_wo     = (const float*)d_in[9];
  const float* e2i_bo     = (const float*)d_in[10];
  const float* i2e_wqkv   = (const float*)d_in[11];
  const float* i2e_bqkv   = (const float*)d_in[12];
  const float* i2e_wo     = (const float*)d_in[13];
  const float* i2e_bo     = (const float*)d_in[14];
  const float* ffn_eda_w1 = (const float*)d_in[15];
  const float* ffn_eda_b1 = (const float*)d_in[16];
  const float* ffn_eda_w2 = (const float*)d_in[17];
  const float* ffn_eda_b2 = (const float*)d_in[18];
  const float* ffn_imu_w1 = (const float*)d_in[19];
  const float* ffn_imu_b1 = (const float*)d_in[20];
  const float* ffn_imu_w2 = (const float*)d_in[21];
  const float* ffn_imu_b2 = (const float*)d_in[22];
  const float* ln_eda1_g  = (const float*)d_in[23];
  const float* ln_eda1_b  = (const float*)d_in[24];
  const float* ln_eda2_g  = (const float*)d_in[25];
  const float* ln_eda2_b  = (const float*)d_in[26];
  const float* ln_imu1_g  = (const float*)d_in[27];
  const float* ln_imu1_b  = (const float*)d_in[28];
  const float* ln_imu2_g  = (const float*)d_in[29];
  const float* ln_imu2_b  = (const float*)d_in[30];
  const float* out_w      = (const float*)d_in[31];
  const float* out_b      = (const float*)d_in[32];
  const float* out_ln_g   = (const float*)d_in[33];
  const float* out_ln_b   = (const float*)d_in[34];

  float*  wsf  = (float*)d_ws;
  __bf16* pack = (__bf16*)((char*)d_ws + WS_PACK_BYTE);

  prep_combine<<<dim3(512), dim3(256), 0, stream>>>(
      e2i_wqkv, e2i_wo, e2i_bqkv, e2i_bo,
      i2e_wqkv, i2e_wo, i2e_bqkv, i2e_bo, wsf);

  prep_pack<<<dim3(960), dim3(64), 0, stream>>>(
      eda_proj_w, imu_proj_w, ffn_eda_w1, ffn_imu_w1,
      ffn_eda_w2, ffn_imu_w2, out_w, wsf, pack);

  fused_fwd<<<dim3(2048), dim3(64), 0, stream>>>(
      tokens, eda_proj_b, eda_cls, imu_proj_b, imu_cls,
      ffn_eda_b1, ffn_eda_b2, ffn_imu_b1, ffn_imu_b2,
      ln_eda1_g, ln_eda1_b, ln_eda2_g, ln_eda2_b,
      ln_imu1_g, ln_imu1_b, ln_imu2_g, ln_imu2_b,
      out_b, out_ln_g, out_ln_b,
      wsf + WS_BC_F, pack, (float*)d_out);
}